// Round 9
// baseline (71953.839 us; speedup 1.0000x reference)
//
#include <hip/hip_runtime.h>
#include <hip/hip_cooperative_groups.h>
#include <hip/hip_fp16.h>
#include <math.h>

namespace cg = cooperative_groups;

#define H      4096
#define SEQ    2048
#define HOR    64
#define NBLK   256
#define NTHR   512
#define NWAVE  (NTHR / 64)
#define RPW    2            // rows per wave; 8 waves * 2 = 16 rows per block
#define J      16           // float4 chunks per lane per row: H/(64*4)

#define NREP       8                     // replicas of the tagged h buffer
#define LINE_F     32                    // floats per 128B line (16 {h,tag} granules)
#define REP_F      (NBLK * LINE_F)       // floats per replica = 8192
#define BUF_F      (NREP * REP_F)        // floats per buffer   = 65536 (256 KB)

#define SMEM_H     (H * 4)               // 16384 B: h vector (fp32)
#define SMEM_R     (NWAVE * RPW * H * 2) // 131072 B: r_Wh rows (fp16, row-pair interleaved uint4)
#define SMEM_RED   192                   // red[8] + pub[16] + cnt + flags8[8]
#define SMEM_BYTES (SMEM_H + SMEM_R + SMEM_RED)

typedef float f32x4_t __attribute__((ext_vector_type(4)));

// ---- fence-free L3-coherent point ops (sc0 sc1 = bypass L1+L2, served by
// memory-side Infinity Cache which is coherent across XCDs). ----
__device__ __forceinline__ void store_l3_f4(float* p, float a, float b, float c, float d) {
    f32x4_t w;
    w.x = a; w.y = b; w.z = c; w.w = d;
    asm volatile("global_store_dwordx4 %0, %1, off sc0 sc1"
                 :: "v"(p), "v"(w) : "memory");
}
__device__ __forceinline__ float4 load_l3_f4(const float4* p) {
    float4 v;
    asm volatile("global_load_dwordx4 %0, %1, off sc0 sc1"
                 : "=v"(v) : "v"(p) : "memory");
    return v;
}
__device__ __forceinline__ void vm_drain() {
    asm volatile("s_waitcnt vmcnt(0)" ::: "memory");
}

__device__ __forceinline__ float wave_reduce(float v) {
#pragma unroll
    for (int o = 32; o > 0; o >>= 1) v += __shfl_xor(v, o, 64);
    return v;
}

__device__ __forceinline__ float dot4(float4 a, float4 b) {
    float s = a.x * b.x;
    s = fmaf(a.y, b.y, s);
    s = fmaf(a.z, b.z, s);
    s = fmaf(a.w, b.w, s);
    return s;
}

union H4U { uint2 u; __half h[4]; };

__device__ __forceinline__ uint2 pack4(float4 v) {
    H4U c;
    c.h[0] = __float2half_rn(v.x); c.h[1] = __float2half_rn(v.y);
    c.h[2] = __float2half_rn(v.z); c.h[3] = __float2half_rn(v.w);
    return c.u;
}

__device__ __forceinline__ float4 unpack4(uint2 p) {
    H4U c; c.u = p;
    return make_float4(__half2float(c.h[0]), __half2float(c.h[1]),
                       __half2float(c.h[2]), __half2float(c.h[3]));
}

// Fully weight-resident persistent GRU.
// R9 = R8's slice-pipelined consumption, re-implemented codegen-safe.
// R8's 4x regression was rule #20: '#pragma unroll' failed on a loop with an
// inner spin-while -> weight arrays runtime-indexed -> scratch spill (FETCH
// 123 GB = weights re-read per step). Here the 8 phases are macro-expanded
// with LITERAL indices; weight arrays can only be statically indexed.
//  - wave w poll-gathers slice w (source blocks 32w..32w+32), stages to hF,
//    lgkmcnt(0), raises LDS flag[w]=t+1.
//  - dot loop = PHASE(0)..PHASE(7): spin on LDS flag[s], memory clobber,
//    then j=2s,2s+1 with compile-time j. Late slices hide under compute.
//  - AR y-reduction after the dot loop (x only feeds the epilogue).
//  - publish: last-arriving wave (LDS counter) stores the block's 8 tagged
//    replica lines before the end barrier (R7-proven).
// Tags: float t (exact to 2112); ws poison 0xAAAAAAAA = -3e-13 < 0 fails
// every tag check; double-buffer + monotone tags rule out WAR races.
__global__ __launch_bounds__(NTHR, 1) void gru_kernel(
    const float* __restrict__ xseq,
    const float* __restrict__ uWx, const float* __restrict__ uWh, const float* __restrict__ ubv,
    const float* __restrict__ rWx, const float* __restrict__ rWh, const float* __restrict__ rbv,
    const float* __restrict__ wxv, const float* __restrict__ Whm, const float* __restrict__ bbv,
    const float* __restrict__ Vv,  const float* __restrict__ cv,
    float* __restrict__ out, float* __restrict__ ws)
{
    cg::grid_group grid = cg::this_grid();
    extern __shared__ unsigned char smem[];
    float* hF  = (float*)smem;                         // h, 4096 fp32
    uint4* rWm = (uint4*)(smem + SMEM_H);              // r_Wh fp16, row-pair interleaved
    float* red = (float*)(smem + SMEM_H + SMEM_R);     // 8 AR partials
    float* pub = red + NWAVE;                          // 16 h-publish slots
    int*   cnt = (int*)(pub + NWAVE * RPW);            // wave-arrival counter
    int*   flags8 = cnt + 8;                           // per-slice ready flags

    const int tid  = threadIdx.x;
    const int wv   = tid >> 6;
    const int lane = tid & 63;
    const int bid  = blockIdx.x;
    const int r0   = bid * (NWAVE * RPW) + wv * RPW;
    const int r1   = r0 + 1;

    float* hA = ws;            // tagged replicated buffer A (65536 floats)
    float* hB = ws + BUF_F;    // tagged replicated buffer B

    if (tid == 0) *cnt = 0;
    if (tid < NWAVE) flags8[tid] = 0;

    // ---- one-time load: pin weights on-chip ----
    const float4* w0p = (const float4*)(Whm + (size_t)r0 * H);
    const float4* w1p = (const float4*)(Whm + (size_t)r1 * H);
    const float4* u0p = (const float4*)(uWh + (size_t)r0 * H);
    const float4* u1p = (const float4*)(uWh + (size_t)r1 * H);
    const float4* p0p = (const float4*)(rWh + (size_t)r0 * H);
    const float4* p1p = (const float4*)(rWh + (size_t)r1 * H);

    float4 wA[J], wB[J];
    uint2  uA[J], uB[J];
    uint4* rsm = rWm + wv * (H / 4);    // 1024 uint4 per wave (both rows)

#pragma unroll
    for (int j = 0; j < J; ++j) {
        const int idx = j * 64 + lane;
        wA[j] = w0p[idx];
        wB[j] = w1p[idx];
        uA[j] = pack4(u0p[idx]);
        uB[j] = pack4(u1p[idx]);
        const uint2 a = pack4(p0p[idx]);
        const uint2 b = pack4(p1p[idx]);
        rsm[idx] = make_uint4(a.x, a.y, b.x, b.y);
    }
#pragma unroll
    for (int j = 0; j < J; ++j) {
        asm volatile("" : "+v"(wA[j].x), "+v"(wA[j].y), "+v"(wA[j].z), "+v"(wA[j].w));
        asm volatile("" : "+v"(wB[j].x), "+v"(wB[j].y), "+v"(wB[j].z), "+v"(wB[j].w));
        asm volatile("" : "+v"(uA[j].x), "+v"(uA[j].y));
        asm volatile("" : "+v"(uB[j].x), "+v"(uB[j].y));
    }

    const float uwx0 = uWx[r0], uwx1 = uWx[r1], ub0 = ubv[r0], ub1 = ubv[r1];
    const float rwx0 = rWx[r0], rwx1 = rWx[r1], rb0 = rbv[r0], rb1 = rbv[r1];
    const float wx0  = wxv[r0], wx1  = wxv[r1], bb0 = bbv[r0], bb1 = bbv[r1];
    const float c0 = cv[0];

    // ---- publish/gather address precompute ----
    const int prep = lane >> 3, psub = lane & 7;
    const int pub_off = prep * REP_F + bid * LINE_F + psub * 4;   // floats
    const int gslot = wv * 32 + (lane >> 1);
    const int ghalf = lane & 1;
    const int gat_off = (bid & (NREP - 1)) * REP_F + gslot * LINE_F + ghalf * 16; // floats
    const int hf4 = gslot * 4 + ghalf * 2;   // hF float4 staging index

    // h0 = 0, tag = 0: seed all replicas of hA (one store instruction/block)
    if (wv == 0)
        store_l3_f4(hA + pub_off, 0.f, 0.f, 0.f, 0.f);

    grid.sync();   // one-time; includes intra-block barrier + vmcnt(0) drain

    const float4* v4g = (const float4*)Vv;
    volatile int* vfl = flags8;
    const float4* hF4 = (const float4*)hF;

#pragma unroll 1
    for (int t = 0; t < SEQ + HOR; ++t) {
        const float* hin  = (t & 1) ? hB : hA;
        float*       hout = (t & 1) ? hA : hB;
        const float tagf  = (float)t;
        const float tagf1 = (float)(t + 1);
        const int   tp1   = t + 1;

        // ---- poll-gather own slice with exponential backoff ----
        const float4* src = (const float4*)(hin + gat_off);
        float4 q0, q1, q2, q3;
        int bk = 0;
        for (;;) {
            q0 = load_l3_f4(src);
            q1 = load_l3_f4(src + 1);
            q2 = load_l3_f4(src + 2);
            q3 = load_l3_f4(src + 3);
            vm_drain();
            const float mn = fminf(fminf(fminf(q0.y, q0.w), fminf(q1.y, q1.w)),
                                   fminf(fminf(q2.y, q2.w), fminf(q3.y, q3.w)));
            if (mn >= tagf) break;
            if      (bk == 0) { bk = 1; }
            else if (bk == 1) { __builtin_amdgcn_s_sleep(1); bk = 2; }
            else if (bk == 2) { __builtin_amdgcn_s_sleep(2); bk = 3; }
            else if (bk == 3) { __builtin_amdgcn_s_sleep(4); bk = 4; }
            else              { __builtin_amdgcn_s_sleep(8); }
        }
        // stage own slice to hF, then raise this slice's LDS flag
        ((float4*)hF)[hf4]     = make_float4(q0.x, q0.z, q1.x, q1.z);
        ((float4*)hF)[hf4 + 1] = make_float4(q2.x, q2.z, q3.x, q3.z);
        asm volatile("s_waitcnt lgkmcnt(0)" ::: "memory");
        if (lane == 0) flags8[wv] = tp1;

        // ---- slice-pipelined six row-dots: 8 static phases ----
        float au0 = 0.f, au1 = 0.f, ar0 = 0.f, ar1 = 0.f, aw0 = 0.f, aw1 = 0.f;

#define DOT_J(j) do {                                                        \
            const int idx_ = (j) * 64 + lane;                                \
            const float4 hv = hF4[idx_];                                     \
            aw0 = fmaf(wA[j].x, hv.x, aw0); aw0 = fmaf(wA[j].y, hv.y, aw0);  \
            aw0 = fmaf(wA[j].z, hv.z, aw0); aw0 = fmaf(wA[j].w, hv.w, aw0);  \
            aw1 = fmaf(wB[j].x, hv.x, aw1); aw1 = fmaf(wB[j].y, hv.y, aw1);  \
            aw1 = fmaf(wB[j].z, hv.z, aw1); aw1 = fmaf(wB[j].w, hv.w, aw1);  \
            const float4 ua4 = unpack4(uA[j]);                               \
            au0 = fmaf(ua4.x, hv.x, au0); au0 = fmaf(ua4.y, hv.y, au0);      \
            au0 = fmaf(ua4.z, hv.z, au0); au0 = fmaf(ua4.w, hv.w, au0);      \
            const float4 ub4 = unpack4(uB[j]);                               \
            au1 = fmaf(ub4.x, hv.x, au1); au1 = fmaf(ub4.y, hv.y, au1);      \
            au1 = fmaf(ub4.z, hv.z, au1); au1 = fmaf(ub4.w, hv.w, au1);      \
            const uint4 m = rsm[idx_];                                       \
            const float4 ra4 = unpack4(make_uint2(m.x, m.y));                \
            ar0 = fmaf(ra4.x, hv.x, ar0); ar0 = fmaf(ra4.y, hv.y, ar0);      \
            ar0 = fmaf(ra4.z, hv.z, ar0); ar0 = fmaf(ra4.w, hv.w, ar0);      \
            const float4 rb4 = unpack4(make_uint2(m.z, m.w));                \
            ar1 = fmaf(rb4.x, hv.x, ar1); ar1 = fmaf(rb4.y, hv.y, ar1);      \
            ar1 = fmaf(rb4.z, hv.z, ar1); ar1 = fmaf(rb4.w, hv.w, ar1);      \
        } while (0)

#define PHASE(s) do {                                                        \
            while (vfl[s] < tp1) {}                                          \
            asm volatile("" ::: "memory");                                   \
            DOT_J(2 * (s));                                                  \
            DOT_J(2 * (s) + 1);                                              \
        } while (0)

        PHASE(0); PHASE(1); PHASE(2); PHASE(3);
        PHASE(4); PHASE(5); PHASE(6); PHASE(7);
#undef PHASE
#undef DOT_J

        au0 = wave_reduce(au0); au1 = wave_reduce(au1);
        ar0 = wave_reduce(ar0); ar1 = wave_reduce(ar1);
        aw0 = wave_reduce(aw0); aw1 = wave_reduce(aw1);

        // ---- x (after dots: hF fully staged; x only feeds the epilogue) ----
        float x;
        if (t < SEQ) {
            x = xseq[t];
        } else {
            float4 a0 = hF4[tid];
            float4 a1 = hF4[tid + NTHR];
            float p = dot4(a0, v4g[tid]) + dot4(a1, v4g[tid + NTHR]);
            p = wave_reduce(p);
            if (lane == 0) red[wv] = p;
            __syncthreads();
            float y = c0;
#pragma unroll
            for (int w = 0; w < NWAVE; ++w) y += red[w];
            x = y;
            if (t > SEQ && bid == 0 && tid == 0) out[t - SEQ - 1] = y;
        }

        // ---- epilogue on lanes 0/1 -> LDS pub slots ----
        if (lane < 2) {
            const bool s = (lane == 1);
            const float adu = s ? au1 : au0;
            const float adr = s ? ar1 : ar0;
            const float adw = s ? aw1 : aw0;
            const float uwx = s ? uwx1 : uwx0, ubb = s ? ub1 : ub0;
            const float rwx = s ? rwx1 : rwx0, rbb = s ? rb1 : rb0;
            const float wxx = s ? wx1  : wx0,  bbb = s ? bb1 : bb0;
            const int   rr  = s ? r1 : r0;
            const float ho  = hF[rr];
            const float zu  = fmaf(uwx, x, adu + ubb);
            const float zr  = fmaf(rwx, x, adr + rbb);
            const float u   = 1.f / (1.f + expf(-zu));
            const float g   = 1.f / (1.f + expf(-zr));
            const float hh  = tanhf(fmaf(wxx, x, fmaf(g, adw, bbb)));
            pub[wv * RPW + (s ? 1 : 0)] = fmaf(u, hh - ho, ho);
        }
        // ensure this wave's pub writes are in LDS before its arrival bump
        asm volatile("s_waitcnt lgkmcnt(0)" ::: "memory");
        int old = 0;
        if (lane == 0) old = atomicAdd(cnt, 1);
        old = __shfl(old, 0, 64);
        if (old == 8 * t + 7) {
            // last-arriving wave: publish the block's 8 tagged replica lines
            const float h0v = pub[psub * 2], h1v = pub[psub * 2 + 1];
            store_l3_f4(hout + pub_off, h0v, tagf1, h1v, tagf1);
        }
        __syncthreads();   // releases hF + pub for next-step stages
    }

    // preds[63] from final h (t=2111 odd wrote hA with tag 2112); block 0 only
    if (bid == 0) {
        const float tagF = (float)(SEQ + HOR);
        const float4* src = (const float4*)(hA + gat_off);
        float4 q0, q1, q2, q3;
        int bk = 0;
        for (;;) {
            q0 = load_l3_f4(src);
            q1 = load_l3_f4(src + 1);
            q2 = load_l3_f4(src + 2);
            q3 = load_l3_f4(src + 3);
            vm_drain();
            const float mn = fminf(fminf(fminf(q0.y, q0.w), fminf(q1.y, q1.w)),
                                   fminf(fminf(q2.y, q2.w), fminf(q3.y, q3.w)));
            if (mn >= tagF) break;
            if      (bk == 0) { bk = 1; }
            else              { __builtin_amdgcn_s_sleep(2); }
        }
        ((float4*)hF)[hf4]     = make_float4(q0.x, q0.z, q1.x, q1.z);
        ((float4*)hF)[hf4 + 1] = make_float4(q2.x, q2.z, q3.x, q3.z);
        __syncthreads();
        float4 a0 = ((const float4*)hF)[tid];
        float4 a1 = ((const float4*)hF)[tid + NTHR];
        float p = dot4(a0, v4g[tid]) + dot4(a1, v4g[tid + NTHR]);
        p = wave_reduce(p);
        if (lane == 0) red[wv] = p;
        __syncthreads();
        if (tid == 0) {
            float y = c0;
            for (int w = 0; w < NWAVE; ++w) y += red[w];
            out[HOR - 1] = y;
        }
    }
}

extern "C" void kernel_launch(void* const* d_in, const int* in_sizes, int n_in,
                              void* d_out, int out_size, void* d_ws, size_t ws_size,
                              hipStream_t stream) {
    const float* xseq = (const float*)d_in[0];
    const float* uWx  = (const float*)d_in[2];
    const float* uWh  = (const float*)d_in[3];
    const float* ubv  = (const float*)d_in[4];
    const float* rWx  = (const float*)d_in[5];
    const float* rWh  = (const float*)d_in[6];
    const float* rbv  = (const float*)d_in[7];
    const float* wxv  = (const float*)d_in[8];
    const float* Whm  = (const float*)d_in[9];
    const float* bbv  = (const float*)d_in[10];
    const float* Vv   = (const float*)d_in[11];
    const float* cv   = (const float*)d_in[12];
    float* out = (float*)d_out;
    float* ws  = (float*)d_ws;

    (void)hipFuncSetAttribute((const void*)gru_kernel,
                              hipFuncAttributeMaxDynamicSharedMemorySize, SMEM_BYTES);

    void* args[] = { &xseq, &uWx, &uWh, &ubv, &rWx, &rWh, &rbv,
                     &wxv, &Whm, &bbv, &Vv, &cv, &out, &ws };
    (void)hipLaunchCooperativeKernel((void*)gru_kernel, dim3(NBLK), dim3(NTHR),
                                     args, SMEM_BYTES, stream);
}

// Round 10
// 10503.073 us; speedup vs baseline: 6.8507x; 6.8507x over previous
//
#include <hip/hip_runtime.h>
#include <hip/hip_cooperative_groups.h>
#include <hip/hip_fp16.h>
#include <math.h>

namespace cg = cooperative_groups;

#define H      4096
#define SEQ    2048
#define HOR    64
#define NBLK   256
#define NTHR   512
#define NWAVE  (NTHR / 64)
#define RPW    2            // rows per wave; 8 waves * 2 = 16 rows per block
#define J      16           // float4 chunks per lane per row: H/(64*4)

#define NREP       8                     // replicas of the tagged h buffer
#define LINE_F     32                    // floats per 128B line (16 {h,tag} granules)
#define REP_F      (NBLK * LINE_F)       // floats per replica = 8192
#define BUF_F      (NREP * REP_F)        // floats per buffer   = 65536 (256 KB)

#define SMEM_H     (H * 4)               // 16384 B: h vector (fp32)
#define SMEM_R     (NWAVE * RPW * H * 2) // 131072 B: r_Wh rows (fp16, row-pair interleaved uint4)
#define SMEM_HH    (H * 2)               // 8192 B: h vector packed fp16 (for fdot2 u/r dots)
#define SMEM_RED   128                   // red[8] + pub[16] + cnt
#define SMEM_BYTES (SMEM_H + SMEM_R + SMEM_HH + SMEM_RED)   // 155776 <= 163840

typedef float f32x4_t __attribute__((ext_vector_type(4)));
typedef _Float16 h2_t __attribute__((ext_vector_type(2)));

__device__ __forceinline__ h2_t as_h2(unsigned u) {
    union { unsigned u; h2_t h; } c; c.u = u; return c.h;
}

// ---- fence-free L3-coherent point ops (sc0 sc1 = bypass L1+L2, served by
// memory-side Infinity Cache which is coherent across XCDs). ----
__device__ __forceinline__ void store_l3_f4(float* p, float a, float b, float c, float d) {
    f32x4_t w;
    w.x = a; w.y = b; w.z = c; w.w = d;
    asm volatile("global_store_dwordx4 %0, %1, off sc0 sc1"
                 :: "v"(p), "v"(w) : "memory");
}
__device__ __forceinline__ float4 load_l3_f4(const float4* p) {
    float4 v;
    asm volatile("global_load_dwordx4 %0, %1, off sc0 sc1"
                 : "=v"(v) : "v"(p) : "memory");
    return v;
}
__device__ __forceinline__ void vm_drain() {
    asm volatile("s_waitcnt vmcnt(0)" ::: "memory");
}

__device__ __forceinline__ float wave_reduce(float v) {
#pragma unroll
    for (int o = 32; o > 0; o >>= 1) v += __shfl_xor(v, o, 64);
    return v;
}

__device__ __forceinline__ float dot4(float4 a, float4 b) {
    float s = a.x * b.x;
    s = fmaf(a.y, b.y, s);
    s = fmaf(a.z, b.z, s);
    s = fmaf(a.w, b.w, s);
    return s;
}

union H4U { uint2 u; __half h[4]; };

__device__ __forceinline__ uint2 pack4(float4 v) {
    H4U c;
    c.h[0] = __float2half_rn(v.x); c.h[1] = __float2half_rn(v.y);
    c.h[2] = __float2half_rn(v.z); c.h[3] = __float2half_rn(v.w);
    return c.u;
}

// Fully weight-resident persistent GRU.
// R10 = R7 (16.7ms, best verified) + fdot2 compute thinning. R8/R9's lesson:
// ANY new control flow inside the dot region breaks AGPR residency of the
// fp32 Wh arrays -> 58MB/step scratch re-reads (FETCH canary). So this round
// changes ONLY straight-line code:
//  - h is staged to LDS twice: fp32 (hF, for Wh dots / V-dot / epilogue ho)
//    and packed fp16 (hH, +8KB LDS) during the same stage step.
//  - u/r row-dots use v_dot2_f32_f16 (__builtin_amdgcn_fdot2): per j,
//    8 fdot2 + 1 ds_read_b64 replace 16 v_cvt_f32_f16 + 16 fma.
//    Wh dots stay fp32 fma (h_hat path keeps full h precision).
// Sync structure byte-identical to R7: backoff poll-gather of tagged replica
// lines, barrier, dots, epilogue, last-arriving-wave publish, barrier.
// Tags: float t (exact to 2112); ws poison 0xAAAAAAAA = -3e-13 < 0 fails
// every tag check; double-buffer + monotone tags rule out WAR races.
__global__ __launch_bounds__(NTHR, 1) void gru_kernel(
    const float* __restrict__ xseq,
    const float* __restrict__ uWx, const float* __restrict__ uWh, const float* __restrict__ ubv,
    const float* __restrict__ rWx, const float* __restrict__ rWh, const float* __restrict__ rbv,
    const float* __restrict__ wxv, const float* __restrict__ Whm, const float* __restrict__ bbv,
    const float* __restrict__ Vv,  const float* __restrict__ cv,
    float* __restrict__ out, float* __restrict__ ws)
{
    cg::grid_group grid = cg::this_grid();
    extern __shared__ unsigned char smem[];
    float* hF  = (float*)smem;                         // h, 4096 fp32
    uint4* rWm = (uint4*)(smem + SMEM_H);              // r_Wh fp16, row-pair interleaved
    uint2* hH2 = (uint2*)(smem + SMEM_H + SMEM_R);     // h packed fp16 (1024 uint2? no: 2048B*4) -- 4 halves per uint2
    float* red = (float*)(smem + SMEM_H + SMEM_R + SMEM_HH);   // 8 AR partials
    float* pub = red + NWAVE;                          // 16 h-publish slots
    int*   cnt = (int*)(pub + NWAVE * RPW);            // wave-arrival counter

    const int tid  = threadIdx.x;
    const int wv   = tid >> 6;
    const int lane = tid & 63;
    const int bid  = blockIdx.x;
    const int r0   = bid * (NWAVE * RPW) + wv * RPW;
    const int r1   = r0 + 1;

    float* hA = ws;            // tagged replicated buffer A (65536 floats)
    float* hB = ws + BUF_F;    // tagged replicated buffer B

    if (tid == 0) *cnt = 0;

    // ---- one-time load: pin weights on-chip ----
    const float4* w0p = (const float4*)(Whm + (size_t)r0 * H);
    const float4* w1p = (const float4*)(Whm + (size_t)r1 * H);
    const float4* u0p = (const float4*)(uWh + (size_t)r0 * H);
    const float4* u1p = (const float4*)(uWh + (size_t)r1 * H);
    const float4* p0p = (const float4*)(rWh + (size_t)r0 * H);
    const float4* p1p = (const float4*)(rWh + (size_t)r1 * H);

    float4 wA[J], wB[J];
    uint2  uA[J], uB[J];
    uint4* rsm = rWm + wv * (H / 4);    // 1024 uint4 per wave (both rows)

#pragma unroll
    for (int j = 0; j < J; ++j) {
        const int idx = j * 64 + lane;
        wA[j] = w0p[idx];
        wB[j] = w1p[idx];
        uA[j] = pack4(u0p[idx]);
        uB[j] = pack4(u1p[idx]);
        const uint2 a = pack4(p0p[idx]);
        const uint2 b = pack4(p1p[idx]);
        rsm[idx] = make_uint4(a.x, a.y, b.x, b.y);
    }
#pragma unroll
    for (int j = 0; j < J; ++j) {
        asm volatile("" : "+v"(wA[j].x), "+v"(wA[j].y), "+v"(wA[j].z), "+v"(wA[j].w));
        asm volatile("" : "+v"(wB[j].x), "+v"(wB[j].y), "+v"(wB[j].z), "+v"(wB[j].w));
        asm volatile("" : "+v"(uA[j].x), "+v"(uA[j].y));
        asm volatile("" : "+v"(uB[j].x), "+v"(uB[j].y));
    }

    const float uwx0 = uWx[r0], uwx1 = uWx[r1], ub0 = ubv[r0], ub1 = ubv[r1];
    const float rwx0 = rWx[r0], rwx1 = rWx[r1], rb0 = rbv[r0], rb1 = rbv[r1];
    const float wx0  = wxv[r0], wx1  = wxv[r1], bb0 = bbv[r0], bb1 = bbv[r1];
    const float c0 = cv[0];

    // ---- publish/gather address precompute ----
    const int prep = lane >> 3, psub = lane & 7;
    const int pub_off = prep * REP_F + bid * LINE_F + psub * 4;   // floats
    const int gslot = wv * 32 + (lane >> 1);
    const int ghalf = lane & 1;
    const int gat_off = (bid & (NREP - 1)) * REP_F + gslot * LINE_F + ghalf * 16; // floats
    const int hf4 = gslot * 4 + ghalf * 2;   // hF float4 staging index (even)

    // h0 = 0, tag = 0: seed all replicas of hA (one store instruction/block)
    if (wv == 0)
        store_l3_f4(hA + pub_off, 0.f, 0.f, 0.f, 0.f);

    grid.sync();   // one-time; includes intra-block barrier + vmcnt(0) drain

    const float4* v4g = (const float4*)Vv;
    const float4* hF4 = (const float4*)hF;

#pragma unroll 1
    for (int t = 0; t < SEQ + HOR; ++t) {
        const float* hin  = (t & 1) ? hB : hA;
        float*       hout = (t & 1) ? hA : hB;
        const float tagf  = (float)t;
        const float tagf1 = (float)(t + 1);

        // ---- poll-gather own slice with exponential backoff ----
        const float4* src = (const float4*)(hin + gat_off);
        float4 q0, q1, q2, q3;
        int bk = 0;
        for (;;) {
            q0 = load_l3_f4(src);
            q1 = load_l3_f4(src + 1);
            q2 = load_l3_f4(src + 2);
            q3 = load_l3_f4(src + 3);
            vm_drain();
            const float mn = fminf(fminf(fminf(q0.y, q0.w), fminf(q1.y, q1.w)),
                                   fminf(fminf(q2.y, q2.w), fminf(q3.y, q3.w)));
            if (mn >= tagf) break;
            if      (bk == 0) { bk = 1; }
            else if (bk == 1) { __builtin_amdgcn_s_sleep(1); bk = 2; }
            else if (bk == 2) { __builtin_amdgcn_s_sleep(2); bk = 3; }
            else if (bk == 3) { __builtin_amdgcn_s_sleep(4); bk = 4; }
            else              { __builtin_amdgcn_s_sleep(8); }
        }
        // stage to hF (fp32) AND hH (packed fp16) -- straight-line
        const float4 sa = make_float4(q0.x, q0.z, q1.x, q1.z);
        const float4 sb = make_float4(q2.x, q2.z, q3.x, q3.z);
        ((float4*)hF)[hf4]     = sa;
        ((float4*)hF)[hf4 + 1] = sb;
        const uint2 pa = pack4(sa), pb = pack4(sb);
        ((uint4*)hH2)[hf4 >> 1] = make_uint4(pa.x, pa.y, pb.x, pb.y);
        __syncthreads();   // hF/hH ready (all waves past previous publish)

        float x;
        if (t < SEQ) {
            x = xseq[t];
        } else {
            // y = v.h + c0, redundantly and identically in every block
            float4 a0 = hF4[tid];
            float4 a1 = hF4[tid + NTHR];
            float p = dot4(a0, v4g[tid]) + dot4(a1, v4g[tid + NTHR]);
            p = wave_reduce(p);
            if (lane == 0) red[wv] = p;
            __syncthreads();
            float y = c0;
#pragma unroll
            for (int w = 0; w < NWAVE; ++w) y += red[w];
            x = y;
            if (t > SEQ && bid == 0 && tid == 0) out[t - SEQ - 1] = y;
        }

        // ---- six resident row-dots: Wh in fp32 fma, u/r via v_dot2_f32_f16 ----
        float au0 = 0.f, au1 = 0.f, ar0 = 0.f, ar1 = 0.f, aw0 = 0.f, aw1 = 0.f;
#pragma unroll
        for (int j = 0; j < J; ++j) {
            const int idx = j * 64 + lane;
            const float4 hv = hF4[idx];
            const uint2  hh = hH2[idx];          // 4 halves of the same h chunk
            aw0 = fmaf(wA[j].x, hv.x, aw0); aw0 = fmaf(wA[j].y, hv.y, aw0);
            aw0 = fmaf(wA[j].z, hv.z, aw0); aw0 = fmaf(wA[j].w, hv.w, aw0);
            aw1 = fmaf(wB[j].x, hv.x, aw1); aw1 = fmaf(wB[j].y, hv.y, aw1);
            aw1 = fmaf(wB[j].z, hv.z, aw1); aw1 = fmaf(wB[j].w, hv.w, aw1);
            au0 = __builtin_amdgcn_fdot2(as_h2(uA[j].x), as_h2(hh.x), au0, false);
            au0 = __builtin_amdgcn_fdot2(as_h2(uA[j].y), as_h2(hh.y), au0, false);
            au1 = __builtin_amdgcn_fdot2(as_h2(uB[j].x), as_h2(hh.x), au1, false);
            au1 = __builtin_amdgcn_fdot2(as_h2(uB[j].y), as_h2(hh.y), au1, false);
            const uint4 m = rsm[idx];
            ar0 = __builtin_amdgcn_fdot2(as_h2(m.x), as_h2(hh.x), ar0, false);
            ar0 = __builtin_amdgcn_fdot2(as_h2(m.y), as_h2(hh.y), ar0, false);
            ar1 = __builtin_amdgcn_fdot2(as_h2(m.z), as_h2(hh.x), ar1, false);
            ar1 = __builtin_amdgcn_fdot2(as_h2(m.w), as_h2(hh.y), ar1, false);
        }
        au0 = wave_reduce(au0); au1 = wave_reduce(au1);
        ar0 = wave_reduce(ar0); ar1 = wave_reduce(ar1);
        aw0 = wave_reduce(aw0); aw1 = wave_reduce(aw1);

        // ---- epilogue on lanes 0/1 -> LDS pub slots ----
        if (lane < 2) {
            const bool s = (lane == 1);
            const float adu = s ? au1 : au0;
            const float adr = s ? ar1 : ar0;
            const float adw = s ? aw1 : aw0;
            const float uwx = s ? uwx1 : uwx0, ubb = s ? ub1 : ub0;
            const float rwx = s ? rwx1 : rwx0, rbb = s ? rb1 : rb0;
            const float wxx = s ? wx1  : wx0,  bbb = s ? bb1 : bb0;
            const int   rr  = s ? r1 : r0;
            const float ho  = hF[rr];
            const float zu  = fmaf(uwx, x, adu + ubb);
            const float zr  = fmaf(rwx, x, adr + rbb);
            const float u   = 1.f / (1.f + expf(-zu));
            const float g   = 1.f / (1.f + expf(-zr));
            const float hh  = tanhf(fmaf(wxx, x, fmaf(g, adw, bbb)));
            pub[wv * RPW + (s ? 1 : 0)] = fmaf(u, hh - ho, ho);
        }
        // ensure this wave's pub writes are in LDS before its arrival bump
        asm volatile("s_waitcnt lgkmcnt(0)" ::: "memory");
        int old = 0;
        if (lane == 0) old = atomicAdd(cnt, 1);
        old = __shfl(old, 0, 64);
        if (old == 8 * t + 7) {
            // last-arriving wave: publish the block's 8 tagged replica lines
            const float h0v = pub[psub * 2], h1v = pub[psub * 2 + 1];
            store_l3_f4(hout + pub_off, h0v, tagf1, h1v, tagf1);
        }
        __syncthreads();   // releases hF/hH + pub for next-step stages
    }

    // preds[63] from final h (t=2111 odd wrote hA with tag 2112); block 0 only
    if (bid == 0) {
        const float tagF = (float)(SEQ + HOR);
        const float4* src = (const float4*)(hA + gat_off);
        float4 q0, q1, q2, q3;
        int bk = 0;
        for (;;) {
            q0 = load_l3_f4(src);
            q1 = load_l3_f4(src + 1);
            q2 = load_l3_f4(src + 2);
            q3 = load_l3_f4(src + 3);
            vm_drain();
            const float mn = fminf(fminf(fminf(q0.y, q0.w), fminf(q1.y, q1.w)),
                                   fminf(fminf(q2.y, q2.w), fminf(q3.y, q3.w)));
            if (mn >= tagF) break;
            if      (bk == 0) { bk = 1; }
            else              { __builtin_amdgcn_s_sleep(2); }
        }
        ((float4*)hF)[hf4]     = make_float4(q0.x, q0.z, q1.x, q1.z);
        ((float4*)hF)[hf4 + 1] = make_float4(q2.x, q2.z, q3.x, q3.z);
        __syncthreads();
        float4 a0 = hF4[tid];
        float4 a1 = hF4[tid + NTHR];
        float p = dot4(a0, v4g[tid]) + dot4(a1, v4g[tid + NTHR]);
        p = wave_reduce(p);
        if (lane == 0) red[wv] = p;
        __syncthreads();
        if (tid == 0) {
            float y = c0;
            for (int w = 0; w < NWAVE; ++w) y += red[w];
            out[HOR - 1] = y;
        }
    }
}

extern "C" void kernel_launch(void* const* d_in, const int* in_sizes, int n_in,
                              void* d_out, int out_size, void* d_ws, size_t ws_size,
                              hipStream_t stream) {
    const float* xseq = (const float*)d_in[0];
    const float* uWx  = (const float*)d_in[2];
    const float* uWh  = (const float*)d_in[3];
    const float* ubv  = (const float*)d_in[4];
    const float* rWx  = (const float*)d_in[5];
    const float* rWh  = (const float*)d_in[6];
    const float* rbv  = (const float*)d_in[7];
    const float* wxv  = (const float*)d_in[8];
    const float* Whm  = (const float*)d_in[9];
    const float* bbv  = (const float*)d_in[10];
    const float* Vv   = (const float*)d_in[11];
    const float* cv   = (const float*)d_in[12];
    float* out = (float*)d_out;
    float* ws  = (float*)d_ws;

    (void)hipFuncSetAttribute((const void*)gru_kernel,
                              hipFuncAttributeMaxDynamicSharedMemorySize, SMEM_BYTES);

    void* args[] = { &xseq, &uWx, &uWh, &ubv, &rWx, &rWh, &rbv,
                     &wxv, &Whm, &bbv, &Vv, &cv, &out, &ws };
    (void)hipLaunchCooperativeKernel((void*)gru_kernel, dim3(NBLK), dim3(NTHR),
                                     args, SMEM_BYTES, stream);
}

// Round 11
// 8758.989 us; speedup vs baseline: 8.2149x; 1.1991x over previous
//
#include <hip/hip_runtime.h>
#include <hip/hip_cooperative_groups.h>
#include <hip/hip_fp16.h>
#include <math.h>

namespace cg = cooperative_groups;

#define H      4096
#define SEQ    2048
#define HOR    64
#define NBLK   256
#define NTHR   512
#define NWAVE  (NTHR / 64)
#define RPW    2            // rows per wave; 8 waves * 2 = 16 rows per block
#define J      16           // float4 chunks per lane per row: H/(64*4)

#define NREP       8                     // replicas of the tagged h buffer
#define LINE_F     32                    // floats per 128B line (16 {h,tag} granules)
#define REP_F      (NBLK * LINE_F)       // floats per replica = 8192
#define BUF_F      (NREP * REP_F)        // floats per buffer   = 65536 (256 KB)

#define SMEM_H     (H * 4)               // 16384 B: h vector (fp32) -- epilogue ho + AR V-dot
#define SMEM_R     (NWAVE * RPW * H * 2) // 131072 B: r_Wh rows (fp16, row-pair interleaved uint4)
#define SMEM_HH    (H * 2)               // 8192 B: h packed fp16 (all six dots)
#define SMEM_RED   128                   // red[8] + pub[16] + cnt
#define SMEM_BYTES (SMEM_H + SMEM_R + SMEM_HH + SMEM_RED)   // 155776 <= 163840

typedef float f32x4_t __attribute__((ext_vector_type(4)));
typedef _Float16 h2_t __attribute__((ext_vector_type(2)));

__device__ __forceinline__ h2_t as_h2(unsigned u) {
    union { unsigned u; h2_t h; } c; c.u = u; return c.h;
}

// ---- fence-free L3-coherent point ops (sc0 sc1 = bypass L1+L2, served by
// memory-side Infinity Cache which is coherent across XCDs). ----
__device__ __forceinline__ void store_l3_f4(float* p, float a, float b, float c, float d) {
    f32x4_t w;
    w.x = a; w.y = b; w.z = c; w.w = d;
    asm volatile("global_store_dwordx4 %0, %1, off sc0 sc1"
                 :: "v"(p), "v"(w) : "memory");
}
__device__ __forceinline__ float4 load_l3_f4(const float4* p) {
    float4 v;
    asm volatile("global_load_dwordx4 %0, %1, off sc0 sc1"
                 : "=v"(v) : "v"(p) : "memory");
    return v;
}
__device__ __forceinline__ void vm_drain() {
    asm volatile("s_waitcnt vmcnt(0)" ::: "memory");
}

__device__ __forceinline__ float wave_reduce(float v) {
#pragma unroll
    for (int o = 32; o > 0; o >>= 1) v += __shfl_xor(v, o, 64);
    return v;
}

__device__ __forceinline__ float dot4(float4 a, float4 b) {
    float s = a.x * b.x;
    s = fmaf(a.y, b.y, s);
    s = fmaf(a.z, b.z, s);
    s = fmaf(a.w, b.w, s);
    return s;
}

union H4U { uint2 u; __half h[4]; };

__device__ __forceinline__ uint2 pack4(float4 v) {
    H4U c;
    c.h[0] = __float2half_rn(v.x); c.h[1] = __float2half_rn(v.y);
    c.h[2] = __float2half_rn(v.z); c.h[3] = __float2half_rn(v.w);
    return c.u;
}

// Fully weight-resident persistent GRU.
// R11 = R10 + Wh dots also via v_dot2_f32_f16 (chain-shortening, part 2).
// R10's lesson: at 1 block/CU the dot region is LATENCY-bound (dependency
// chains, no TLP) -- fdot2 halved the u/r chains and won 2.9us/step. This
// round converts the remaining 8 fp32 fmas/j (Wh rows) to 4 fdot2/j:
//  - Wh pinned as packed fp16 uint2[J] x 2 rows (64 VGPRs, was 128 as fp32),
//  - dot body per j: 12 fdot2 + hH(b64) + rsm(b128); the hF b128 read is gone,
//  - hF (fp32) still staged: epilogue ho and AR V-dot stay fp32.
// Straight-line only -- no new control flow anywhere near the dot region
// (R8/R9: any spin inside it breaks AGPR residency -> 58MB/step scratch).
// Sync structure byte-identical to R7/R10: backoff poll-gather of tagged
// replica lines, barrier, dots, epilogue, last-arriving-wave publish, barrier.
// Tags: float t (exact to 2112); ws poison 0xAAAAAAAA = -3e-13 < 0 fails
// every tag check; double-buffer + monotone tags rule out WAR races.
__global__ __launch_bounds__(NTHR, 1) void gru_kernel(
    const float* __restrict__ xseq,
    const float* __restrict__ uWx, const float* __restrict__ uWh, const float* __restrict__ ubv,
    const float* __restrict__ rWx, const float* __restrict__ rWh, const float* __restrict__ rbv,
    const float* __restrict__ wxv, const float* __restrict__ Whm, const float* __restrict__ bbv,
    const float* __restrict__ Vv,  const float* __restrict__ cv,
    float* __restrict__ out, float* __restrict__ ws)
{
    cg::grid_group grid = cg::this_grid();
    extern __shared__ unsigned char smem[];
    float* hF  = (float*)smem;                         // h, 4096 fp32
    uint4* rWm = (uint4*)(smem + SMEM_H);              // r_Wh fp16, row-pair interleaved
    uint2* hH2 = (uint2*)(smem + SMEM_H + SMEM_R);     // h packed fp16
    float* red = (float*)(smem + SMEM_H + SMEM_R + SMEM_HH);   // 8 AR partials
    float* pub = red + NWAVE;                          // 16 h-publish slots
    int*   cnt = (int*)(pub + NWAVE * RPW);            // wave-arrival counter

    const int tid  = threadIdx.x;
    const int wv   = tid >> 6;
    const int lane = tid & 63;
    const int bid  = blockIdx.x;
    const int r0   = bid * (NWAVE * RPW) + wv * RPW;
    const int r1   = r0 + 1;

    float* hA = ws;            // tagged replicated buffer A (65536 floats)
    float* hB = ws + BUF_F;    // tagged replicated buffer B

    if (tid == 0) *cnt = 0;

    // ---- one-time load: pin weights on-chip (all fp16-packed now) ----
    const float4* w0p = (const float4*)(Whm + (size_t)r0 * H);
    const float4* w1p = (const float4*)(Whm + (size_t)r1 * H);
    const float4* u0p = (const float4*)(uWh + (size_t)r0 * H);
    const float4* u1p = (const float4*)(uWh + (size_t)r1 * H);
    const float4* p0p = (const float4*)(rWh + (size_t)r0 * H);
    const float4* p1p = (const float4*)(rWh + (size_t)r1 * H);

    uint2  wpA[J], wpB[J];     // Wh rows, packed fp16
    uint2  uA[J], uB[J];       // u_Wh rows, packed fp16
    uint4* rsm = rWm + wv * (H / 4);    // 1024 uint4 per wave (both r rows)

#pragma unroll
    for (int j = 0; j < J; ++j) {
        const int idx = j * 64 + lane;
        wpA[j] = pack4(w0p[idx]);
        wpB[j] = pack4(w1p[idx]);
        uA[j]  = pack4(u0p[idx]);
        uB[j]  = pack4(u1p[idx]);
        const uint2 a = pack4(p0p[idx]);
        const uint2 b = pack4(p1p[idx]);
        rsm[idx] = make_uint4(a.x, a.y, b.x, b.y);
    }
#pragma unroll
    for (int j = 0; j < J; ++j) {
        asm volatile("" : "+v"(wpA[j].x), "+v"(wpA[j].y));
        asm volatile("" : "+v"(wpB[j].x), "+v"(wpB[j].y));
        asm volatile("" : "+v"(uA[j].x), "+v"(uA[j].y));
        asm volatile("" : "+v"(uB[j].x), "+v"(uB[j].y));
    }

    const float uwx0 = uWx[r0], uwx1 = uWx[r1], ub0 = ubv[r0], ub1 = ubv[r1];
    const float rwx0 = rWx[r0], rwx1 = rWx[r1], rb0 = rbv[r0], rb1 = rbv[r1];
    const float wx0  = wxv[r0], wx1  = wxv[r1], bb0 = bbv[r0], bb1 = bbv[r1];
    const float c0 = cv[0];

    // ---- publish/gather address precompute ----
    const int prep = lane >> 3, psub = lane & 7;
    const int pub_off = prep * REP_F + bid * LINE_F + psub * 4;   // floats
    const int gslot = wv * 32 + (lane >> 1);
    const int ghalf = lane & 1;
    const int gat_off = (bid & (NREP - 1)) * REP_F + gslot * LINE_F + ghalf * 16; // floats
    const int hf4 = gslot * 4 + ghalf * 2;   // hF float4 staging index (even)

    // h0 = 0, tag = 0: seed all replicas of hA (one store instruction/block)
    if (wv == 0)
        store_l3_f4(hA + pub_off, 0.f, 0.f, 0.f, 0.f);

    grid.sync();   // one-time; includes intra-block barrier + vmcnt(0) drain

    const float4* v4g = (const float4*)Vv;
    const float4* hF4 = (const float4*)hF;

#pragma unroll 1
    for (int t = 0; t < SEQ + HOR; ++t) {
        const float* hin  = (t & 1) ? hB : hA;
        float*       hout = (t & 1) ? hA : hB;
        const float tagf  = (float)t;
        const float tagf1 = (float)(t + 1);

        // ---- poll-gather own slice with exponential backoff ----
        const float4* src = (const float4*)(hin + gat_off);
        float4 q0, q1, q2, q3;
        int bk = 0;
        for (;;) {
            q0 = load_l3_f4(src);
            q1 = load_l3_f4(src + 1);
            q2 = load_l3_f4(src + 2);
            q3 = load_l3_f4(src + 3);
            vm_drain();
            const float mn = fminf(fminf(fminf(q0.y, q0.w), fminf(q1.y, q1.w)),
                                   fminf(fminf(q2.y, q2.w), fminf(q3.y, q3.w)));
            if (mn >= tagf) break;
            if      (bk == 0) { bk = 1; }
            else if (bk == 1) { __builtin_amdgcn_s_sleep(1); bk = 2; }
            else if (bk == 2) { __builtin_amdgcn_s_sleep(2); bk = 3; }
            else if (bk == 3) { __builtin_amdgcn_s_sleep(4); bk = 4; }
            else              { __builtin_amdgcn_s_sleep(8); }
        }
        // stage to hF (fp32) AND hH (packed fp16) -- straight-line
        const float4 sa = make_float4(q0.x, q0.z, q1.x, q1.z);
        const float4 sb = make_float4(q2.x, q2.z, q3.x, q3.z);
        ((float4*)hF)[hf4]     = sa;
        ((float4*)hF)[hf4 + 1] = sb;
        const uint2 pa = pack4(sa), pb = pack4(sb);
        ((uint4*)hH2)[hf4 >> 1] = make_uint4(pa.x, pa.y, pb.x, pb.y);
        __syncthreads();   // hF/hH ready (all waves past previous publish)

        float x;
        if (t < SEQ) {
            x = xseq[t];
        } else {
            // y = v.h + c0, redundantly and identically in every block
            float4 a0 = hF4[tid];
            float4 a1 = hF4[tid + NTHR];
            float p = dot4(a0, v4g[tid]) + dot4(a1, v4g[tid + NTHR]);
            p = wave_reduce(p);
            if (lane == 0) red[wv] = p;
            __syncthreads();
            float y = c0;
#pragma unroll
            for (int w = 0; w < NWAVE; ++w) y += red[w];
            x = y;
            if (t > SEQ && bid == 0 && tid == 0) out[t - SEQ - 1] = y;
        }

        // ---- six resident row-dots, all via v_dot2_f32_f16 ----
        float au0 = 0.f, au1 = 0.f, ar0 = 0.f, ar1 = 0.f, aw0 = 0.f, aw1 = 0.f;
#pragma unroll
        for (int j = 0; j < J; ++j) {
            const int idx = j * 64 + lane;
            const uint2  hh = hH2[idx];          // 4 halves of this h chunk
            aw0 = __builtin_amdgcn_fdot2(as_h2(wpA[j].x), as_h2(hh.x), aw0, false);
            aw0 = __builtin_amdgcn_fdot2(as_h2(wpA[j].y), as_h2(hh.y), aw0, false);
            aw1 = __builtin_amdgcn_fdot2(as_h2(wpB[j].x), as_h2(hh.x), aw1, false);
            aw1 = __builtin_amdgcn_fdot2(as_h2(wpB[j].y), as_h2(hh.y), aw1, false);
            au0 = __builtin_amdgcn_fdot2(as_h2(uA[j].x), as_h2(hh.x), au0, false);
            au0 = __builtin_amdgcn_fdot2(as_h2(uA[j].y), as_h2(hh.y), au0, false);
            au1 = __builtin_amdgcn_fdot2(as_h2(uB[j].x), as_h2(hh.x), au1, false);
            au1 = __builtin_amdgcn_fdot2(as_h2(uB[j].y), as_h2(hh.y), au1, false);
            const uint4 m = rsm[idx];
            ar0 = __builtin_amdgcn_fdot2(as_h2(m.x), as_h2(hh.x), ar0, false);
            ar0 = __builtin_amdgcn_fdot2(as_h2(m.y), as_h2(hh.y), ar0, false);
            ar1 = __builtin_amdgcn_fdot2(as_h2(m.z), as_h2(hh.x), ar1, false);
            ar1 = __builtin_amdgcn_fdot2(as_h2(m.w), as_h2(hh.y), ar1, false);
        }
        au0 = wave_reduce(au0); au1 = wave_reduce(au1);
        ar0 = wave_reduce(ar0); ar1 = wave_reduce(ar1);
        aw0 = wave_reduce(aw0); aw1 = wave_reduce(aw1);

        // ---- epilogue on lanes 0/1 -> LDS pub slots ----
        if (lane < 2) {
            const bool s = (lane == 1);
            const float adu = s ? au1 : au0;
            const float adr = s ? ar1 : ar0;
            const float adw = s ? aw1 : aw0;
            const float uwx = s ? uwx1 : uwx0, ubb = s ? ub1 : ub0;
            const float rwx = s ? rwx1 : rwx0, rbb = s ? rb1 : rb0;
            const float wxx = s ? wx1  : wx0,  bbb = s ? bb1 : bb0;
            const int   rr  = s ? r1 : r0;
            const float ho  = hF[rr];
            const float zu  = fmaf(uwx, x, adu + ubb);
            const float zr  = fmaf(rwx, x, adr + rbb);
            const float u   = 1.f / (1.f + expf(-zu));
            const float g   = 1.f / (1.f + expf(-zr));
            const float hh  = tanhf(fmaf(wxx, x, fmaf(g, adw, bbb)));
            pub[wv * RPW + (s ? 1 : 0)] = fmaf(u, hh - ho, ho);
        }
        // ensure this wave's pub writes are in LDS before its arrival bump
        asm volatile("s_waitcnt lgkmcnt(0)" ::: "memory");
        int old = 0;
        if (lane == 0) old = atomicAdd(cnt, 1);
        old = __shfl(old, 0, 64);
        if (old == 8 * t + 7) {
            // last-arriving wave: publish the block's 8 tagged replica lines
            const float h0v = pub[psub * 2], h1v = pub[psub * 2 + 1];
            store_l3_f4(hout + pub_off, h0v, tagf1, h1v, tagf1);
        }
        __syncthreads();   // releases hF/hH + pub for next-step stages
    }

    // preds[63] from final h (t=2111 odd wrote hA with tag 2112); block 0 only
    if (bid == 0) {
        const float tagF = (float)(SEQ + HOR);
        const float4* src = (const float4*)(hA + gat_off);
        float4 q0, q1, q2, q3;
        int bk = 0;
        for (;;) {
            q0 = load_l3_f4(src);
            q1 = load_l3_f4(src + 1);
            q2 = load_l3_f4(src + 2);
            q3 = load_l3_f4(src + 3);
            vm_drain();
            const float mn = fminf(fminf(fminf(q0.y, q0.w), fminf(q1.y, q1.w)),
                                   fminf(fminf(q2.y, q2.w), fminf(q3.y, q3.w)));
            if (mn >= tagF) break;
            if      (bk == 0) { bk = 1; }
            else              { __builtin_amdgcn_s_sleep(2); }
        }
        ((float4*)hF)[hf4]     = make_float4(q0.x, q0.z, q1.x, q1.z);
        ((float4*)hF)[hf4 + 1] = make_float4(q2.x, q2.z, q3.x, q3.z);
        __syncthreads();
        float4 a0 = hF4[tid];
        float4 a1 = hF4[tid + NTHR];
        float p = dot4(a0, v4g[tid]) + dot4(a1, v4g[tid + NTHR]);
        p = wave_reduce(p);
        if (lane == 0) red[wv] = p;
        __syncthreads();
        if (tid == 0) {
            float y = c0;
            for (int w = 0; w < NWAVE; ++w) y += red[w];
            out[HOR - 1] = y;
        }
    }
}

extern "C" void kernel_launch(void* const* d_in, const int* in_sizes, int n_in,
                              void* d_out, int out_size, void* d_ws, size_t ws_size,
                              hipStream_t stream) {
    const float* xseq = (const float*)d_in[0];
    const float* uWx  = (const float*)d_in[2];
    const float* uWh  = (const float*)d_in[3];
    const float* ubv  = (const float*)d_in[4];
    const float* rWx  = (const float*)d_in[5];
    const float* rWh  = (const float*)d_in[6];
    const float* rbv  = (const float*)d_in[7];
    const float* wxv  = (const float*)d_in[8];
    const float* Whm  = (const float*)d_in[9];
    const float* bbv  = (const float*)d_in[10];
    const float* Vv   = (const float*)d_in[11];
    const float* cv   = (const float*)d_in[12];
    float* out = (float*)d_out;
    float* ws  = (float*)d_ws;

    (void)hipFuncSetAttribute((const void*)gru_kernel,
                              hipFuncAttributeMaxDynamicSharedMemorySize, SMEM_BYTES);

    void* args[] = { &xseq, &uWx, &uWh, &ubv, &rWx, &rWh, &rbv,
                     &wxv, &Whm, &bbv, &Vv, &cv, &out, &ws };
    (void)hipLaunchCooperativeKernel((void*)gru_kernel, dim3(NBLK), dim3(NTHR),
                                     args, SMEM_BYTES, stream);
}